// Round 1
// baseline (976.232 us; speedup 1.0000x reference)
//
#include <hip/hip_runtime.h>

#define B_ 128
#define T_ 25
#define V_ 10000

typedef short bf16x8 __attribute__((ext_vector_type(8)));
typedef float f32x4 __attribute__((ext_vector_type(4)));

__device__ __forceinline__ short f2bf(float x) {
  union { float f; unsigned u; } v; v.f = x;
  unsigned r = (v.u + 0x7fffu + ((v.u >> 16) & 1u)) >> 16;
  return (short)r;
}
__device__ __forceinline__ float sigm(float z) { return 1.f / (1.f + __expf(-z)); }
__device__ __forceinline__ float tanhfast(float z) {
  float e = __expf(2.f * z);
  return 1.f - 2.f / (e + 1.f);
}

// ---------------- transpose + cast f32[R,C] -> bf16[C,R] ----------------
__global__ void tcast(const float* __restrict__ src, short* __restrict__ dst, int R, int C) {
  __shared__ float t[32][33];
  int rt0 = blockIdx.y * 32, ct0 = blockIdx.x * 32;
  int tx = threadIdx.x, ty = threadIdx.y; // 32x8
#pragma unroll
  for (int i = 0; i < 4; i++) {
    int r = rt0 + ty + i * 8, c = ct0 + tx;
    if (r < R && c < C) t[ty + i * 8][tx] = src[(size_t)r * C + c];
  }
  __syncthreads();
#pragma unroll
  for (int i = 0; i < 4; i++) {
    int c = ct0 + ty + i * 8, r = rt0 + tx;
    if (r < R && c < C) dst[(size_t)c * R + r] = f2bf(t[tx][ty + i * 8]);
  }
}

// ---------------- build X0 [T*B, 1024] bf16 : [emb(tok) | cnn] ----------------
__global__ void build_x0(const int* __restrict__ tok, const float* __restrict__ emb,
                         const float* __restrict__ cnn, short* __restrict__ X0) {
  int row = blockIdx.x;           // t*128 + b
  int t = row >> 7, b = row & 127;
  int tk = tok[b * T_ + t];
  const float* er = emb + (size_t)tk * 512;
  short* dst = X0 + (size_t)row * 1024;
  for (int i = threadIdx.x; i < 1024; i += 256)
    dst[i] = f2bf(i < 512 ? er[i] : cnn[b * 512 + (i - 512)]);
}

// ---------------- init hidden state ----------------
__global__ void init_h(const float* __restrict__ ihs, float* h0f, float* h1f, short* xh1b) {
  int i = blockIdx.x * 256 + threadIdx.x;  // 0 .. 65535
  if (i < 65536) {
    int b = i >> 9, h = i & 511;
    float v0 = ihs[i], v1 = ihs[65536 + i];
    h0f[i] = v0; h1f[i] = v1;
    xh1b[b * 1024 + h] = f2bf(v0);
    xh1b[b * 1024 + 512 + h] = f2bf(v1);
  }
}

__global__ void write_final(const float* __restrict__ h0f, const float* __restrict__ h1f,
                            float* __restrict__ out) {
  int i = blockIdx.x * 256 + threadIdx.x;
  if (i < 65536) {
    out[32000000 + i] = h0f[i];
    out[32000000 + 65536 + i] = h1f[i];
  }
}

// ---------------- generic MFMA GEMM with fused epilogues ----------------
struct GP {
  const short* A; const short* Bt;
  int lda, ldb, N, K;
  const float* ainit;                       // A0 slice (t-offset) for VAR 1/2
  const float* bias0; const float* bias1; const float* bias2;
  float* uf; float* hf;
  short* w0; short* w1;
  float* fdst;
  float* outp; const float* bout;
};

template<int BM, int BN, int VAR>
__device__ __forceinline__ void gemm_core(const GP& p) {
  __shared__ alignas(16) short la[BM][40];
  __shared__ alignas(16) short lb[BN][40];
  const int bm = blockIdx.y, bn = blockIdx.x;
  const int tid = threadIdx.x;
  const int wave = tid >> 6, lane = tid & 63;
  const int wm = wave >> 1, wn = wave & 1;
  constexpr int WM = BM / 2, WN = BN / 2;
  constexpr int MF = WM / 16, NF = WN / 16;
  const int lr = lane & 15, lg = lane >> 4;
  f32x4 acc[MF][NF] = {};
  for (int k0 = 0; k0 < p.K; k0 += 32) {
    __syncthreads();
    for (int i = tid; i < BM * 4; i += 256) {
      int r = i >> 2, c8 = (i & 3) * 8;
      *(bf16x8*)&la[r][c8] = *(const bf16x8*)&p.A[(size_t)(bm * BM + r) * p.lda + k0 + c8];
    }
    for (int i = tid; i < BN * 4; i += 256) {
      int r = i >> 2, c8 = (i & 3) * 8;
      int gn = bn * BN + r;
      bf16x8 v = {};
      if (gn < p.N) v = *(const bf16x8*)&p.Bt[(size_t)gn * p.ldb + k0 + c8];
      *(bf16x8*)&lb[r][c8] = v;
    }
    __syncthreads();
    bf16x8 af[MF], bfr[NF];
#pragma unroll
    for (int m = 0; m < MF; m++) af[m] = *(bf16x8*)&la[wm * WM + m * 16 + lr][lg * 8];
#pragma unroll
    for (int n = 0; n < NF; n++) bfr[n] = *(bf16x8*)&lb[wn * WN + n * 16 + lr][lg * 8];
#pragma unroll
    for (int m = 0; m < MF; m++)
#pragma unroll
      for (int n = 0; n < NF; n++)
        acc[m][n] = __builtin_amdgcn_mfma_f32_16x16x32_bf16(af[m], bfr[n], acc[m][n], 0, 0, 0);
  }
#pragma unroll
  for (int m = 0; m < MF; m++)
#pragma unroll
    for (int n = 0; n < NF; n++)
#pragma unroll
      for (int i = 0; i < 4; i++) {
        int row = bm * BM + wm * WM + m * 16 + lg * 4 + i;
        int col = bn * BN + wn * WN + n * 16 + lr;
        if (col >= p.N) continue;
        float v = acc[m][n][i];
        if constexpr (VAR == 0) {           // A0 = x@Wx + bias (3 gates)
          float bias = col < 512 ? p.bias0[col] : (col < 1024 ? p.bias1[col - 512] : p.bias2[col - 1024]);
          p.fdst[(size_t)row * 1536 + col] = v + bias;
        } else if constexpr (VAR == 1) {    // layer0 u,r
          float z = v + p.ainit[(size_t)row * 1536 + col];
          float s = sigm(z);
          if (col < 512) p.uf[row * 512 + col] = s;
          else { int c = col - 512; p.w0[row * 512 + c] = f2bf(s * p.hf[row * 512 + c]); }
        } else if constexpr (VAR == 2) {    // layer0 cand + h0 update
          float z = v + p.ainit[(size_t)row * 1536 + 1024 + col];
          float c = tanhfast(z);
          float u = p.uf[row * 512 + col], h = p.hf[row * 512 + col];
          float hn = u * h + (1.f - u) * c;
          p.hf[row * 512 + col] = hn;
          short hb = f2bf(hn);
          p.w0[row * 1024 + col] = hb;      // xh1b[:,0:512]
          p.w1[row * 1024 + col] = hb;      // xc1b[par][:,0:512]
        } else if constexpr (VAR == 3) {    // layer1 u,r
          float z = v + (col < 512 ? p.bias0[col] : p.bias1[col - 512]);
          float s = sigm(z);
          if (col < 512) p.uf[row * 512 + col] = s;
          else { int c = col - 512; p.w0[row * 1024 + 512 + c] = f2bf(s * p.hf[row * 512 + c]); }
        } else if constexpr (VAR == 4) {    // layer1 cand + h1 update
          float z = v + p.bias2[col];
          float cc = tanhfast(z);
          float u = p.uf[row * 512 + col], h = p.hf[row * 512 + col];
          float hn = u * h + (1.f - u) * cc;
          p.hf[row * 512 + col] = hn;
          p.w0[row * 1024 + 512 + col] = f2bf(hn);  // xh1b[:,512:]
          p.w1[row * 512 + col] = f2bf(hn);         // H1all[t]
        } else {                            // VAR 5: logits, out[b,t,v]
          p.outp[(size_t)(row & 127) * (T_ * V_) + (size_t)(row >> 7) * V_ + col] = v + p.bout[col];
        }
      }
}

template<int BM, int BN, int VAR>
__global__ __launch_bounds__(256) void gemm_one(GP p) { gemm_core<BM, BN, VAR>(p); }

template<int BM, int BN, int VA, int VB>
__global__ __launch_bounds__(256) void gemm_dual(GP a, GP b) {
  if (blockIdx.z == 0) gemm_core<BM, BN, VA>(a);
  else                 gemm_core<BM, BN, VB>(b);
}

// ---------------- host ----------------
extern "C" void kernel_launch(void* const* d_in, const int* in_sizes, int n_in,
                              void* d_out, int out_size, void* d_ws, size_t ws_size,
                              hipStream_t stream) {
  const int*   tokens = (const int*)  d_in[0];
  const float* cnn    = (const float*)d_in[1];
  const float* ihs    = (const float*)d_in[2];
  const float* emb    = (const float*)d_in[3];
  const float* Wu0 = (const float*)d_in[4];
  const float* Wr0 = (const float*)d_in[5];
  const float* Wc0 = (const float*)d_in[6];
  const float* bu0 = (const float*)d_in[7];
  const float* br0 = (const float*)d_in[8];
  const float* bc0 = (const float*)d_in[9];
  const float* Wu1 = (const float*)d_in[10];
  const float* Wr1 = (const float*)d_in[11];
  const float* Wc1 = (const float*)d_in[12];
  const float* bu1 = (const float*)d_in[13];
  const float* br1 = (const float*)d_in[14];
  const float* bc1 = (const float*)d_in[15];
  const float* Wout = (const float*)d_in[16];
  const float* bout = (const float*)d_in[17];
  float* out = (float*)d_out;

  char* w = (char*)d_ws;
  size_t off = 0;
  auto alloc = [&](size_t bytes) { void* p = w + off; off += (bytes + 255) & ~255ull; return p; };
  short* WxT    = (short*)alloc(1536 * 1024 * 2);   // [1536,1024] gate-major u,r,c (x part)
  short* Whur0T = (short*)alloc(1024 * 512 * 2);    // [1024,512]
  short* Whc0T  = (short*)alloc(512 * 512 * 2);     // [512,512]
  short* W1urT  = (short*)alloc(1024 * 1024 * 2);   // [1024,1024]
  short* Wc1T   = (short*)alloc(512 * 1024 * 2);    // [512,1024]
  short* WoutT  = (short*)alloc((size_t)10000 * 512 * 2);
  short* X0     = (short*)alloc((size_t)3200 * 1024 * 2);
  float* A0     = (float*)alloc((size_t)3200 * 1536 * 4);
  short* H1all  = (short*)alloc((size_t)3200 * 512 * 2);
  float* u0f    = (float*)alloc(128 * 512 * 4);
  float* u1f    = (float*)alloc(128 * 512 * 4);
  float* h0f    = (float*)alloc(128 * 512 * 4);
  float* h1f    = (float*)alloc(128 * 512 * 4);
  short* rh0b   = (short*)alloc(128 * 512 * 2);
  short* xh1b   = (short*)alloc(128 * 1024 * 2);
  short* xc1b0  = (short*)alloc(128 * 1024 * 2);
  short* xc1b1  = (short*)alloc(128 * 1024 * 2);
  (void)ws_size; (void)in_sizes; (void)n_in; (void)out_size;

  dim3 tb(32, 8);
  // weight transposes (f32 -> bf16, B^T layout [N,K])
  tcast<<<dim3(16, 32), tb, 0, stream>>>(Wu0, WxT,                1024, 512);
  tcast<<<dim3(16, 32), tb, 0, stream>>>(Wr0, WxT + 512 * 1024,   1024, 512);
  tcast<<<dim3(16, 32), tb, 0, stream>>>(Wc0, WxT + 1024 * 1024,  1024, 512);
  tcast<<<dim3(16, 16), tb, 0, stream>>>(Wu0 + 1024 * 512, Whur0T,            512, 512);
  tcast<<<dim3(16, 16), tb, 0, stream>>>(Wr0 + 1024 * 512, Whur0T + 512 * 512, 512, 512);
  tcast<<<dim3(16, 16), tb, 0, stream>>>(Wc0 + 1024 * 512, Whc0T,             512, 512);
  tcast<<<dim3(16, 32), tb, 0, stream>>>(Wu1, W1urT,              1024, 512);
  tcast<<<dim3(16, 32), tb, 0, stream>>>(Wr1, W1urT + 512 * 1024, 1024, 512);
  tcast<<<dim3(16, 32), tb, 0, stream>>>(Wc1, Wc1T,               1024, 512);
  tcast<<<dim3(313, 16), tb, 0, stream>>>(Wout, WoutT,            512, 10000);

  build_x0<<<3200, 256, 0, stream>>>(tokens, emb, cnn, X0);
  init_h<<<256, 256, 0, stream>>>(ihs, h0f, h1f, xh1b);

  // A0 = X0 @ WxT^T + biases : [3200,1536]
  {
    GP g = {};
    g.A = X0; g.lda = 1024; g.Bt = WxT; g.ldb = 1024; g.N = 1536; g.K = 1024;
    g.bias0 = bu0; g.bias1 = br0; g.bias2 = bc0; g.fdst = A0;
    gemm_one<128, 128, 0><<<dim3(12, 25), 256, 0, stream>>>(g);
  }

  auto mkP1 = [&](int t) {
    GP g = {};
    g.A = xh1b; g.lda = 1024; g.Bt = Whur0T; g.ldb = 512; g.N = 1024; g.K = 512;
    g.ainit = A0 + (size_t)t * 128 * 1536; g.uf = u0f; g.hf = h0f; g.w0 = rh0b;
    return g;
  };
  auto mkP2 = [&](int t) {
    GP g = {};
    g.A = rh0b; g.lda = 512; g.Bt = Whc0T; g.ldb = 512; g.N = 512; g.K = 512;
    g.ainit = A0 + (size_t)t * 128 * 1536; g.uf = u0f; g.hf = h0f;
    g.w0 = xh1b; g.w1 = (t & 1) ? xc1b1 : xc1b0;
    return g;
  };
  auto mkP3 = [&](int t) {
    GP g = {};
    g.A = xh1b; g.lda = 1024; g.Bt = W1urT; g.ldb = 1024; g.N = 1024; g.K = 1024;
    g.bias0 = bu1; g.bias1 = br1; g.uf = u1f; g.hf = h1f;
    g.w0 = (t & 1) ? xc1b1 : xc1b0;
    return g;
  };
  auto mkP4 = [&](int t) {
    GP g = {};
    g.A = (t & 1) ? xc1b1 : xc1b0; g.lda = 1024; g.Bt = Wc1T; g.ldb = 1024; g.N = 512; g.K = 1024;
    g.bias2 = bc1; g.uf = u1f; g.hf = h1f;
    g.w0 = xh1b; g.w1 = H1all + (size_t)t * 128 * 512;
    return g;
  };

  // boot: layer-0 of step 0
  { GP g = mkP1(0); gemm_one<32, 32, 1><<<dim3(32, 4), 256, 0, stream>>>(g); }
  { GP g = mkP2(0); gemm_one<32, 32, 2><<<dim3(16, 4), 256, 0, stream>>>(g); }

  // pipelined: phase A_t = {P3(t), P1(t+1)}, phase B_t = {P4(t), P2(t+1)}
  for (int t = 0; t < T_; t++) {
    if (t < T_ - 1) {
      GP a = mkP3(t), b = mkP1(t + 1);
      gemm_dual<32, 32, 3, 1><<<dim3(32, 4, 2), 256, 0, stream>>>(a, b);
      GP c = mkP4(t), d = mkP2(t + 1);
      gemm_dual<32, 32, 4, 2><<<dim3(16, 4, 2), 256, 0, stream>>>(c, d);
    } else {
      GP a = mkP3(t); gemm_one<32, 32, 3><<<dim3(32, 4), 256, 0, stream>>>(a);
      GP c = mkP4(t); gemm_one<32, 32, 4><<<dim3(16, 4), 256, 0, stream>>>(c);
    }
  }

  // logits = H1all @ WoutT^T + bout -> out[b,t,v]
  {
    GP g = {};
    g.A = H1all; g.lda = 512; g.Bt = WoutT; g.ldb = 512; g.N = 10000; g.K = 512;
    g.outp = out; g.bout = bout;
    gemm_one<128, 128, 5><<<dim3(79, 25), 256, 0, stream>>>(g);
  }

  write_final<<<256, 256, 0, stream>>>(h0f, h1f, out);
}

// Round 2
// 622.203 us; speedup vs baseline: 1.5690x; 1.5690x over previous
//
#include <hip/hip_runtime.h>

#define B_ 128
#define T_ 25
#define V_ 10000

typedef short bf16x8 __attribute__((ext_vector_type(8)));
typedef float f32x4 __attribute__((ext_vector_type(4)));

__device__ __forceinline__ short f2bf(float x) {
  union { float f; unsigned u; } v; v.f = x;
  unsigned r = (v.u + 0x7fffu + ((v.u >> 16) & 1u)) >> 16;
  return (short)r;
}
__device__ __forceinline__ float sigm(float z) { return 1.f / (1.f + __expf(-z)); }
__device__ __forceinline__ float tanhfast(float z) {
  float e = __expf(2.f * z);
  return 1.f - 2.f / (e + 1.f);
}

__device__ __forceinline__ void gload_lds16(const void* g, void* l) {
  __builtin_amdgcn_global_load_lds((const __attribute__((address_space(1))) void*)g,
                                   (__attribute__((address_space(3))) void*)l, 16, 0, 0);
}

// ---------------- merged transpose + cast f32[R,C] -> bf16[C,R] ----------------
struct TJob { const float* src; short* dst; int R, C, t0; };
struct TJobs { TJob j[10]; };

__global__ void tcast_all(TJobs J) {
  __shared__ float t[32][33];
  int bid = blockIdx.x;
  int ji = 0;
  while (ji < 9 && bid >= J.j[ji + 1].t0) ji++;
  const float* src = J.j[ji].src;
  short* dst = J.j[ji].dst;
  int R = J.j[ji].R, C = J.j[ji].C;
  int rel = bid - J.j[ji].t0;
  int ctiles = (C + 31) >> 5;
  int rt0 = (rel / ctiles) * 32, ct0 = (rel % ctiles) * 32;
  int tx = threadIdx.x, ty = threadIdx.y; // 32x8
#pragma unroll
  for (int i = 0; i < 4; i++) {
    int r = rt0 + ty + i * 8, c = ct0 + tx;
    if (r < R && c < C) t[ty + i * 8][tx] = src[(size_t)r * C + c];
  }
  __syncthreads();
#pragma unroll
  for (int i = 0; i < 4; i++) {
    int c = ct0 + ty + i * 8, r = rt0 + tx;
    if (r < R && c < C) dst[(size_t)c * R + r] = f2bf(t[tx][ty + i * 8]);
  }
}

// ---------------- build X0 [T*B, 1024] bf16 : [emb(tok) | cnn] ----------------
__global__ void build_x0(const int* __restrict__ tok, const float* __restrict__ emb,
                         const float* __restrict__ cnn, short* __restrict__ X0) {
  int row = blockIdx.x;           // t*128 + b
  int t = row >> 7, b = row & 127;
  int tk = tok[b * T_ + t];
  const float* er = emb + (size_t)tk * 512;
  short* dst = X0 + (size_t)row * 1024;
  for (int i = threadIdx.x; i < 1024; i += 256)
    dst[i] = f2bf(i < 512 ? er[i] : cnn[b * 512 + (i - 512)]);
}

// ---------------- init hidden state ----------------
__global__ void init_h(const float* __restrict__ ihs, float* h0f, float* h1f, short* xh1b) {
  int i = blockIdx.x * 256 + threadIdx.x;  // 0 .. 65535
  if (i < 65536) {
    int b = i >> 9, h = i & 511;
    float v0 = ihs[i], v1 = ihs[65536 + i];
    h0f[i] = v0; h1f[i] = v1;
    xh1b[b * 1024 + h] = f2bf(v0);
    xh1b[b * 1024 + 512 + h] = f2bf(v1);
  }
}

__global__ void write_final(const float* __restrict__ h0f, const float* __restrict__ h1f,
                            float* __restrict__ out) {
  int i = blockIdx.x * 256 + threadIdx.x;
  if (i < 65536) {
    out[32000000 + i] = h0f[i];
    out[32000000 + 65536 + i] = h1f[i];
  }
}

// ---------------- MFMA GEMM core: global_load_lds + XOR-swizzle + dbuf ----------------
struct GP {
  const short* A; const short* Bt;
  int lda, ldb, N, K;
  const float* ainit;                       // A0 slice (t-offset) for VAR 1/2
  const float* bias0; const float* bias1; const float* bias2;
  float* uf; float* hf;
  short* w0; short* w1;
  float* fdst;
  float* outp; const float* bout;
};

// LDS tile: ROWS x 64 bf16, linear rows of 128B = 8 granules of 16B.
// Stored granule (row,gc) holds source granule gc ^ (row&7)  [rule-21 involution].
template<int BM, int BN, int VAR>
__device__ __forceinline__ void gemm_core(const GP& p, short* la, short* lb) {
  const int bm = blockIdx.y, bn = blockIdx.x;
  const int tid = threadIdx.x;
  const int wave = tid >> 6, lane = tid & 63;
  const int wm = wave >> 1, wn = wave & 1;
  constexpr int WM = BM / 2, WN = BN / 2;
  constexpr int MF = WM / 16, NF = WN / 16;
  const int lr = lane & 15, lg = lane >> 4;
  const short* Abase = p.A + (size_t)bm * BM * p.lda;
  const short* Bbase = p.Bt + (size_t)bn * BN * p.ldb;
  const int bnmax = p.N - bn * BN;          // valid rows in B tile (>=1)
  f32x4 acc[MF][NF] = {};
  const int nkb = p.K >> 6;

  auto stA = [&](int buf, int k0) {
    constexpr int NI = BM / 32;             // 256-thread issues per buffer
#pragma unroll
    for (int j = 0; j < NI; j++) {
      int glin = j * 256 + tid;
      int row = glin >> 3, gc = glin & 7;
      int gcs = gc ^ (row & 7);
      gload_lds16(Abase + (size_t)row * p.lda + k0 + gcs * 8,
                  &la[buf * BM * 64 + j * 2048 + wave * 512]);
    }
  };
  auto stB = [&](int buf, int k0) {
    constexpr int NI = BN / 32;
#pragma unroll
    for (int j = 0; j < NI; j++) {
      int glin = j * 256 + tid;
      int row = glin >> 3, gc = glin & 7;
      int gcs = gc ^ (row & 7);
      int rc = row < bnmax ? row : bnmax - 1;
      gload_lds16(Bbase + (size_t)rc * p.ldb + k0 + gcs * 8,
                  &lb[buf * BN * 64 + j * 2048 + wave * 512]);
    }
  };

  stA(0, 0); stB(0, 0);
  __syncthreads();                           // vmcnt(0) drain by compiler
  int buf = 0;
  for (int kb = 0; kb < nkb; kb++) {
    if (kb + 1 < nkb) { stA(buf ^ 1, (kb + 1) * 64); stB(buf ^ 1, (kb + 1) * 64); }
    bf16x8 af[2][MF], bfr[2][NF];
#pragma unroll
    for (int ks = 0; ks < 2; ks++) {
#pragma unroll
      for (int m = 0; m < MF; m++) {
        int ar = wm * WM + m * 16 + lr;
        af[ks][m] = *(const bf16x8*)&la[buf * BM * 64 + (ar * 8 + ((ks * 4 + lg) ^ (ar & 7))) * 8];
      }
#pragma unroll
      for (int n = 0; n < NF; n++) {
        int br = wn * WN + n * 16 + lr;
        bfr[ks][n] = *(const bf16x8*)&lb[buf * BN * 64 + (br * 8 + ((ks * 4 + lg) ^ (br & 7))) * 8];
      }
    }
#pragma unroll
    for (int ks = 0; ks < 2; ks++)
#pragma unroll
      for (int m = 0; m < MF; m++)
#pragma unroll
        for (int n = 0; n < NF; n++)
          acc[m][n] = __builtin_amdgcn_mfma_f32_16x16x32_bf16(af[ks][m], bfr[ks][n], acc[m][n], 0, 0, 0);
    __syncthreads();                         // drains prefetch vmcnt + lds reads
    buf ^= 1;
  }

#pragma unroll
  for (int m = 0; m < MF; m++)
#pragma unroll
    for (int n = 0; n < NF; n++)
#pragma unroll
      for (int i = 0; i < 4; i++) {
        int row = bm * BM + wm * WM + m * 16 + lg * 4 + i;
        int col = bn * BN + wn * WN + n * 16 + lr;
        if (col >= p.N) continue;
        float v = acc[m][n][i];
        if constexpr (VAR == 0) {           // A0 = x@Wx + bias (3 gates)
          float bias = col < 512 ? p.bias0[col] : (col < 1024 ? p.bias1[col - 512] : p.bias2[col - 1024]);
          p.fdst[(size_t)row * 1536 + col] = v + bias;
        } else if constexpr (VAR == 1) {    // layer0 u,r
          float z = v + p.ainit[(size_t)row * 1536 + col];
          float s = sigm(z);
          if (col < 512) p.uf[row * 512 + col] = s;
          else { int c = col - 512; p.w0[row * 512 + c] = f2bf(s * p.hf[row * 512 + c]); }
        } else if constexpr (VAR == 2) {    // layer0 cand + h0 update
          float z = v + p.ainit[(size_t)row * 1536 + 1024 + col];
          float c = tanhfast(z);
          float u = p.uf[row * 512 + col], h = p.hf[row * 512 + col];
          float hn = u * h + (1.f - u) * c;
          p.hf[row * 512 + col] = hn;
          short hb = f2bf(hn);
          p.w0[row * 1024 + col] = hb;      // xh1b[:,0:512]
          p.w1[row * 1024 + col] = hb;      // xc1b[par][:,0:512]
        } else if constexpr (VAR == 3) {    // layer1 u,r
          float z = v + (col < 512 ? p.bias0[col] : p.bias1[col - 512]);
          float s = sigm(z);
          if (col < 512) p.uf[row * 512 + col] = s;
          else { int c = col - 512; p.w0[row * 1024 + 512 + c] = f2bf(s * p.hf[row * 512 + c]); }
        } else if constexpr (VAR == 4) {    // layer1 cand + h1 update
          float z = v + p.bias2[col];
          float cc = tanhfast(z);
          float u = p.uf[row * 512 + col], h = p.hf[row * 512 + col];
          float hn = u * h + (1.f - u) * cc;
          p.hf[row * 512 + col] = hn;
          p.w0[row * 1024 + 512 + col] = f2bf(hn);  // xh1b[:,512:]
          p.w1[row * 512 + col] = f2bf(hn);         // H1all[t]
        } else {                            // VAR 5: logits, out[b,t,v]
          p.outp[(size_t)(row & 127) * (T_ * V_) + (size_t)(row >> 7) * V_ + col] = v + p.bout[col];
        }
      }
}

template<int BM, int BN, int VAR>
__global__ __launch_bounds__(256) void gemm_one(GP p) {
  __shared__ short smem[2 * BM * 64 + 2 * BN * 64];
  gemm_core<BM, BN, VAR>(p, smem, smem + 2 * BM * 64);
}

template<int BM, int BN, int VA, int VB>
__global__ __launch_bounds__(256) void gemm_dual(GP a, GP b) {
  __shared__ short smem[2 * BM * 64 + 2 * BN * 64];
  if (blockIdx.z == 0) gemm_core<BM, BN, VA>(a, smem, smem + 2 * BM * 64);
  else                 gemm_core<BM, BN, VB>(b, smem, smem + 2 * BM * 64);
}

// ---------------- host ----------------
extern "C" void kernel_launch(void* const* d_in, const int* in_sizes, int n_in,
                              void* d_out, int out_size, void* d_ws, size_t ws_size,
                              hipStream_t stream) {
  const int*   tokens = (const int*)  d_in[0];
  const float* cnn    = (const float*)d_in[1];
  const float* ihs    = (const float*)d_in[2];
  const float* emb    = (const float*)d_in[3];
  const float* Wu0 = (const float*)d_in[4];
  const float* Wr0 = (const float*)d_in[5];
  const float* Wc0 = (const float*)d_in[6];
  const float* bu0 = (const float*)d_in[7];
  const float* br0 = (const float*)d_in[8];
  const float* bc0 = (const float*)d_in[9];
  const float* Wu1 = (const float*)d_in[10];
  const float* Wr1 = (const float*)d_in[11];
  const float* Wc1 = (const float*)d_in[12];
  const float* bu1 = (const float*)d_in[13];
  const float* br1 = (const float*)d_in[14];
  const float* bc1 = (const float*)d_in[15];
  const float* Wout = (const float*)d_in[16];
  const float* bout = (const float*)d_in[17];
  float* out = (float*)d_out;

  char* w = (char*)d_ws;
  size_t off = 0;
  auto alloc = [&](size_t bytes) { void* p = w + off; off += (bytes + 255) & ~255ull; return p; };
  short* WxT    = (short*)alloc(1536 * 1024 * 2);   // [1536,1024] gate-major u,r,c (x part)
  short* Whur0T = (short*)alloc(1024 * 512 * 2);    // [1024,512]
  short* Whc0T  = (short*)alloc(512 * 512 * 2);     // [512,512]
  short* W1urT  = (short*)alloc(1024 * 1024 * 2);   // [1024,1024]
  short* Wc1T   = (short*)alloc(512 * 1024 * 2);    // [512,1024]
  short* WoutT  = (short*)alloc((size_t)10000 * 512 * 2);
  short* X0     = (short*)alloc((size_t)3200 * 1024 * 2);
  float* A0     = (float*)alloc((size_t)3200 * 1536 * 4);
  short* H1all  = (short*)alloc((size_t)3200 * 512 * 2);
  float* u0f    = (float*)alloc(128 * 512 * 4);
  float* u1f    = (float*)alloc(128 * 512 * 4);
  float* h0f    = (float*)alloc(128 * 512 * 4);
  float* h1f    = (float*)alloc(128 * 512 * 4);
  short* rh0b   = (short*)alloc(128 * 512 * 2);
  short* xh1b   = (short*)alloc(128 * 1024 * 2);
  short* xc1b0  = (short*)alloc(128 * 1024 * 2);
  short* xc1b1  = (short*)alloc(128 * 1024 * 2);
  (void)ws_size; (void)in_sizes; (void)n_in; (void)out_size;

  // merged weight transposes (f32 -> bf16, B^T layout [N,K])
  {
    TJobs J;
    J.j[0] = { Wu0,              WxT,                1024, 512,  0    };
    J.j[1] = { Wr0,              WxT + 512 * 1024,   1024, 512,  512  };
    J.j[2] = { Wc0,              WxT + 1024 * 1024,  1024, 512,  1024 };
    J.j[3] = { Wu0 + 1024 * 512, Whur0T,             512,  512,  1536 };
    J.j[4] = { Wr0 + 1024 * 512, Whur0T + 512 * 512, 512,  512,  1792 };
    J.j[5] = { Wc0 + 1024 * 512, Whc0T,              512,  512,  2048 };
    J.j[6] = { Wu1,              W1urT,              1024, 512,  2304 };
    J.j[7] = { Wr1,              W1urT + 512 * 1024, 1024, 512,  2816 };
    J.j[8] = { Wc1,              Wc1T,               1024, 512,  3328 };
    J.j[9] = { Wout,             WoutT,              512,  10000, 3840 };
    tcast_all<<<8848, dim3(32, 8), 0, stream>>>(J);
  }

  build_x0<<<3200, 256, 0, stream>>>(tokens, emb, cnn, X0);
  init_h<<<256, 256, 0, stream>>>(ihs, h0f, h1f, xh1b);

  // A0 = X0 @ WxT^T + biases : [3200,1536]
  {
    GP g = {};
    g.A = X0; g.lda = 1024; g.Bt = WxT; g.ldb = 1024; g.N = 1536; g.K = 1024;
    g.bias0 = bu0; g.bias1 = br0; g.bias2 = bc0; g.fdst = A0;
    gemm_one<128, 128, 0><<<dim3(12, 25), 256, 0, stream>>>(g);
  }

  auto mkP1 = [&](int t) {
    GP g = {};
    g.A = xh1b; g.lda = 1024; g.Bt = Whur0T; g.ldb = 512; g.N = 1024; g.K = 512;
    g.ainit = A0 + (size_t)t * 128 * 1536; g.uf = u0f; g.hf = h0f; g.w0 = rh0b;
    return g;
  };
  auto mkP2 = [&](int t) {
    GP g = {};
    g.A = rh0b; g.lda = 512; g.Bt = Whc0T; g.ldb = 512; g.N = 512; g.K = 512;
    g.ainit = A0 + (size_t)t * 128 * 1536; g.uf = u0f; g.hf = h0f;
    g.w0 = xh1b; g.w1 = (t & 1) ? xc1b1 : xc1b0;
    return g;
  };
  auto mkP3 = [&](int t) {
    GP g = {};
    g.A = xh1b; g.lda = 1024; g.Bt = W1urT; g.ldb = 1024; g.N = 1024; g.K = 1024;
    g.bias0 = bu1; g.bias1 = br1; g.uf = u1f; g.hf = h1f;
    g.w0 = (t & 1) ? xc1b1 : xc1b0;
    return g;
  };
  auto mkP4 = [&](int t) {
    GP g = {};
    g.A = (t & 1) ? xc1b1 : xc1b0; g.lda = 1024; g.Bt = Wc1T; g.ldb = 1024; g.N = 512; g.K = 1024;
    g.bias2 = bc1; g.uf = u1f; g.hf = h1f;
    g.w0 = xh1b; g.w1 = H1all + (size_t)t * 128 * 512;
    return g;
  };

  // boot: layer-0 of step 0
  { GP g = mkP1(0); gemm_one<32, 32, 1><<<dim3(32, 4), 256, 0, stream>>>(g); }
  { GP g = mkP2(0); gemm_one<32, 32, 2><<<dim3(16, 4), 256, 0, stream>>>(g); }

  // pipelined: phase A_t = {P3(t), P1(t+1)}, phase B_t = {P4(t), P2(t+1)}
  for (int t = 0; t < T_; t++) {
    if (t < T_ - 1) {
      GP a = mkP3(t), b = mkP1(t + 1);
      gemm_dual<32, 32, 3, 1><<<dim3(32, 4, 2), 256, 0, stream>>>(a, b);
      GP c = mkP4(t), d = mkP2(t + 1);
      gemm_dual<32, 32, 4, 2><<<dim3(16, 4, 2), 256, 0, stream>>>(c, d);
    } else {
      GP a = mkP3(t); gemm_one<32, 32, 3><<<dim3(32, 4), 256, 0, stream>>>(a);
      GP c = mkP4(t); gemm_one<32, 32, 4><<<dim3(16, 4), 256, 0, stream>>>(c);
    }
  }

  // logits = H1all @ WoutT^T + bout -> out[b,t,v]
  {
    GP g = {};
    g.A = H1all; g.lda = 512; g.Bt = WoutT; g.ldb = 512; g.N = 10000; g.K = 512;
    g.outp = out; g.bout = bout;
    gemm_one<128, 128, 5><<<dim3(79, 25), 256, 0, stream>>>(g);
  }

  write_final<<<256, 256, 0, stream>>>(h0f, h1f, out);
}